// Round 2
// baseline (1564.647 us; speedup 1.0000x reference)
//
#include <hip/hip_runtime.h>
#include <math.h>

#define D_   512
#define H_   8
#define DK_  64
#define FF_  2048
#define S_   2048
#define B_   4
#define M_   (B_*S_)     // 8192
#define EPS_ 1e-5f
#define NEG_ -1.0e9f

// ---------------------------------------------------------------------------
// Generic fp32 GEMM: C[m, n0+n] = act(A[m,:] @ W[:, n0+n] + bias[n0+n])
// A: row-major M x K (stride K). W: row-major K x N_full (stride ldw).
// C row stride ldc, block writes cols [bx*BN, bx*BN+BN).
// 256 threads; TM x TN register tile per thread.
// ---------------------------------------------------------------------------
template<int BM, int BN, int TM, int TN, bool RELU>
__global__ __launch_bounds__(256)
void gemm_kernel(const float* __restrict__ A, const float* __restrict__ W, int ldw,
                 const float* __restrict__ bias, float* __restrict__ C, int ldc, int K)
{
    constexpr int BK = 16;
    constexpr int TX = BN / TN;
    constexpr int TY = BM / TM;
    static_assert(TX * TY == 256, "256 threads");

    __shared__ float As[BK][BM + 4];   // transposed: As[k][m]
    __shared__ float Bs[BK][BN + 4];

    const int tid = threadIdx.x;
    const int tx  = tid % TX;
    const int ty  = tid / TX;
    const int n0  = blockIdx.x * BN;
    const int m0  = blockIdx.y * BM;

    float acc[TM][TN];
#pragma unroll
    for (int i = 0; i < TM; i++)
#pragma unroll
        for (int j = 0; j < TN; j++) acc[i][j] = 0.f;

    constexpr int nA = (BM * BK) / (256 * 4);   // float4 loads per thread (A)
    constexpr int nB = (BN * BK) / (256 * 4);

    for (int k0 = 0; k0 < K; k0 += BK) {
        __syncthreads();
        // ---- stage A tile (BM x BK), transposed into As[k][m]
#pragma unroll
        for (int i = 0; i < nA; i++) {
            int f  = tid + i * 256;
            int m  = f >> 2;            // BK/4 = 4 float4 per row
            int kc = (f & 3) * 4;
            const float4 a = *(const float4*)(A + (size_t)(m0 + m) * K + k0 + kc);
            As[kc + 0][m] = a.x;
            As[kc + 1][m] = a.y;
            As[kc + 2][m] = a.z;
            As[kc + 3][m] = a.w;
        }
        // ---- stage B tile (BK x BN)
#pragma unroll
        for (int i = 0; i < nB; i++) {
            int f  = tid + i * 256;
            int kk = f / (BN / 4);
            int c4 = f % (BN / 4);
            *(float4*)(&Bs[kk][c4 * 4]) =
                *(const float4*)(W + (size_t)(k0 + kk) * ldw + n0 + c4 * 4);
        }
        __syncthreads();
        // ---- compute
#pragma unroll
        for (int k = 0; k < BK; k++) {
            float ra[TM], rb[TN];
#pragma unroll
            for (int i = 0; i < TM; i++) ra[i] = As[k][ty * TM + i];
#pragma unroll
            for (int j = 0; j < TN; j++) rb[j] = Bs[k][tx * TN + j];
#pragma unroll
            for (int i = 0; i < TM; i++)
#pragma unroll
                for (int j = 0; j < TN; j++) acc[i][j] = fmaf(ra[i], rb[j], acc[i][j]);
        }
    }

    // ---- epilogue
    float bb[TN];
#pragma unroll
    for (int j = 0; j < TN; j++) bb[j] = bias[n0 + tx * TN + j];

#pragma unroll
    for (int i = 0; i < TM; i++) {
        const size_t row = (size_t)(m0 + ty * TM + i) * ldc + n0 + tx * TN;
#pragma unroll
        for (int j4 = 0; j4 < TN / 4; j4++) {
            float4 o;
            float v0 = acc[i][j4 * 4 + 0] + bb[j4 * 4 + 0];
            float v1 = acc[i][j4 * 4 + 1] + bb[j4 * 4 + 1];
            float v2 = acc[i][j4 * 4 + 2] + bb[j4 * 4 + 2];
            float v3 = acc[i][j4 * 4 + 3] + bb[j4 * 4 + 3];
            if (RELU) {
                v0 = fmaxf(v0, 0.f); v1 = fmaxf(v1, 0.f);
                v2 = fmaxf(v2, 0.f); v3 = fmaxf(v3, 0.f);
            }
            o.x = v0; o.y = v1; o.z = v2; o.w = v3;
            *(float4*)(C + row + j4 * 4) = o;
        }
    }
}

// ---------------------------------------------------------------------------
// Flash attention (causal), fp32. qkv layout: [B*S, 1536] = [q(512)|k(512)|v(512)],
// head h occupies cols h*64..h*64+63 of each segment.
// ctx output: [B*S, 512] row-major (b, s, h*64+dk).
// Block: 64 q-rows, 256 threads (16x16 grid, 4x4 fragments). Loop over k-blocks.
// ---------------------------------------------------------------------------
__global__ __launch_bounds__(256)
void attn_kernel(const float* __restrict__ qkv, float* __restrict__ ctx)
{
    constexpr int LP = 65;                 // +1 pad: 2-way-max bank conflicts (free)
    __shared__ float Qs[64][LP];
    __shared__ float Ks[64][LP];           // reused as P after scores computed
    __shared__ float Vs[64][LP];
    float* Ps = &Ks[0][0];

    const int tid = threadIdx.x;
    const int tx  = tid & 15;
    const int ty  = tid >> 4;
    const int r0  = ty * 4;
    const int c0  = tx * 4;
    const int qb  = 31 - blockIdx.x;       // heavy (large qb) blocks dispatch first
    const int bh  = blockIdx.y;            // 0..31
    const int b   = bh >> 3;
    const int hh  = bh & 7;

    const float* qbase = qkv + (size_t)(b * S_) * 1536 + hh * 64;
    const float* kbase = qbase + 512;
    const float* vbase = qbase + 1024;

    // ---- load Q tile (rows qb*64 .. +63)
#pragma unroll
    for (int i = 0; i < 4; i++) {
        int f  = tid + i * 256;
        int rr = f >> 4;
        int c4 = (f & 15) * 4;
        const float4 q4 = *(const float4*)(qbase + (size_t)(qb * 64 + rr) * 1536 + c4);
        Qs[rr][c4 + 0] = q4.x; Qs[rr][c4 + 1] = q4.y;
        Qs[rr][c4 + 2] = q4.z; Qs[rr][c4 + 3] = q4.w;
    }

    float O[4][4];
#pragma unroll
    for (int i = 0; i < 4; i++)
#pragma unroll
        for (int j = 0; j < 4; j++) O[i][j] = 0.f;
    float mrow[4] = {-INFINITY, -INFINITY, -INFINITY, -INFINITY};
    float lrow[4] = {0.f, 0.f, 0.f, 0.f};

    const float scale = 0.125f;            // 1/sqrt(64)

    for (int kb = 0; kb <= qb; kb++) {
        __syncthreads();                   // prior-iter P/V readers done
        // ---- stage K, V tiles
#pragma unroll
        for (int i = 0; i < 4; i++) {
            int f  = tid + i * 256;
            int rr = f >> 4;
            int c4 = (f & 15) * 4;
            const size_t gofs = (size_t)(kb * 64 + rr) * 1536 + c4;
            const float4 k4 = *(const float4*)(kbase + gofs);
            Ks[rr][c4 + 0] = k4.x; Ks[rr][c4 + 1] = k4.y;
            Ks[rr][c4 + 2] = k4.z; Ks[rr][c4 + 3] = k4.w;
            const float4 v4 = *(const float4*)(vbase + gofs);
            Vs[rr][c4 + 0] = v4.x; Vs[rr][c4 + 1] = v4.y;
            Vs[rr][c4 + 2] = v4.z; Vs[rr][c4 + 3] = v4.w;
        }
        __syncthreads();

        // ---- scores s = (Q @ K^T) * scale, fragment 4x4
        float s[4][4];
#pragma unroll
        for (int i = 0; i < 4; i++)
#pragma unroll
            for (int j = 0; j < 4; j++) s[i][j] = 0.f;
        for (int d = 0; d < 64; d++) {
            float qv[4], kv[4];
#pragma unroll
            for (int i = 0; i < 4; i++) qv[i] = Qs[r0 + i][d];
#pragma unroll
            for (int j = 0; j < 4; j++) kv[j] = Ks[c0 + j][d];
#pragma unroll
            for (int i = 0; i < 4; i++)
#pragma unroll
                for (int j = 0; j < 4; j++) s[i][j] = fmaf(qv[i], kv[j], s[i][j]);
        }
        // scale + causal mask (only diagonal block needs masking)
        if (kb == qb) {
#pragma unroll
            for (int i = 0; i < 4; i++) {
                const int qg = qb * 64 + r0 + i;
#pragma unroll
                for (int j = 0; j < 4; j++) {
                    const int kg = kb * 64 + c0 + j;
                    s[i][j] = (kg > qg) ? NEG_ : s[i][j] * scale;
                }
            }
        } else {
#pragma unroll
            for (int i = 0; i < 4; i++)
#pragma unroll
                for (int j = 0; j < 4; j++) s[i][j] *= scale;
        }

        // ---- online softmax update
        float alpha_i[4];
#pragma unroll
        for (int i = 0; i < 4; i++) {
            float rmax = fmaxf(fmaxf(s[i][0], s[i][1]), fmaxf(s[i][2], s[i][3]));
#pragma unroll
            for (int m = 1; m < 16; m <<= 1) rmax = fmaxf(rmax, __shfl_xor(rmax, m));
            const float mnew = fmaxf(mrow[i], rmax);
            alpha_i[i] = __expf(mrow[i] - mnew);     // 0 on first iter (-inf)
            float rsum = 0.f;
#pragma unroll
            for (int j = 0; j < 4; j++) {
                s[i][j] = __expf(s[i][j] - mnew);    // becomes p
                rsum += s[i][j];
            }
#pragma unroll
            for (int m = 1; m < 16; m <<= 1) rsum += __shfl_xor(rsum, m);
            lrow[i] = lrow[i] * alpha_i[i] + rsum;
            mrow[i] = mnew;
#pragma unroll
            for (int c = 0; c < 4; c++) O[i][c] *= alpha_i[i];
        }

        __syncthreads();                   // everyone done reading Ks
        // ---- stage P (aliases Ks)
#pragma unroll
        for (int i = 0; i < 4; i++)
#pragma unroll
            for (int j = 0; j < 4; j++) Ps[(r0 + i) * LP + (c0 + j)] = s[i][j];
        __syncthreads();

        // ---- O += P @ V  (O fragment: rows r0.., dk cols c0..)
        for (int j = 0; j < 64; j++) {
            float pv[4], vv[4];
#pragma unroll
            for (int i = 0; i < 4; i++) pv[i] = Ps[(r0 + i) * LP + j];
#pragma unroll
            for (int c = 0; c < 4; c++) vv[c] = Vs[j][c0 + c];
#pragma unroll
            for (int i = 0; i < 4; i++)
#pragma unroll
                for (int c = 0; c < 4; c++) O[i][c] = fmaf(pv[i], vv[c], O[i][c]);
        }
    }

    // ---- normalize + write ctx
#pragma unroll
    for (int i = 0; i < 4; i++) {
        const float inv = 1.f / lrow[i];
        float4 o;
        o.x = O[i][0] * inv; o.y = O[i][1] * inv;
        o.z = O[i][2] * inv; o.w = O[i][3] * inv;
        *(float4*)(ctx + (size_t)(b * S_ + qb * 64 + r0 + i) * 512 + hh * 64 + c0) = o;
    }
}

// ---------------------------------------------------------------------------
// out_row = LayerNorm(a_row + r_row) * g + be.  One wave per row (D=512).
// ---------------------------------------------------------------------------
__global__ __launch_bounds__(256)
void addln_kernel(const float* __restrict__ a, const float* __restrict__ r,
                  const float* __restrict__ g, const float* __restrict__ be,
                  float* __restrict__ out)
{
    const int wave = threadIdx.x >> 6;
    const int lane = threadIdx.x & 63;
    const int row  = blockIdx.x * 4 + wave;
    const float* pa = a + (size_t)row * D_;
    const float* pr = r + (size_t)row * D_;
    const int c0 = lane * 4;

    float v[8];
    {
        const float4 a0 = *(const float4*)(pa + c0);
        const float4 r0 = *(const float4*)(pr + c0);
        v[0] = a0.x + r0.x; v[1] = a0.y + r0.y; v[2] = a0.z + r0.z; v[3] = a0.w + r0.w;
        const float4 a1 = *(const float4*)(pa + c0 + 256);
        const float4 r1 = *(const float4*)(pr + c0 + 256);
        v[4] = a1.x + r1.x; v[5] = a1.y + r1.y; v[6] = a1.z + r1.z; v[7] = a1.w + r1.w;
    }

    float sum = 0.f;
#pragma unroll
    for (int i = 0; i < 8; i++) sum += v[i];
#pragma unroll
    for (int m = 1; m < 64; m <<= 1) sum += __shfl_xor(sum, m);
    const float mu = sum * (1.f / D_);

    float sq = 0.f;
#pragma unroll
    for (int i = 0; i < 8; i++) { const float d = v[i] - mu; sq += d * d; }
#pragma unroll
    for (int m = 1; m < 64; m <<= 1) sq += __shfl_xor(sq, m);
    const float rstd = rsqrtf(sq * (1.f / D_) + EPS_);

    const float4 g0  = *(const float4*)(g + c0);
    const float4 b0  = *(const float4*)(be + c0);
    const float4 g1  = *(const float4*)(g + c0 + 256);
    const float4 b1  = *(const float4*)(be + c0 + 256);

    float4 o0, o1;
    o0.x = (v[0] - mu) * rstd * g0.x + b0.x;
    o0.y = (v[1] - mu) * rstd * g0.y + b0.y;
    o0.z = (v[2] - mu) * rstd * g0.z + b0.z;
    o0.w = (v[3] - mu) * rstd * g0.w + b0.w;
    o1.x = (v[4] - mu) * rstd * g1.x + b1.x;
    o1.y = (v[5] - mu) * rstd * g1.y + b1.y;
    o1.z = (v[6] - mu) * rstd * g1.z + b1.z;
    o1.w = (v[7] - mu) * rstd * g1.w + b1.w;
    *(float4*)(out + (size_t)row * D_ + c0)       = o0;
    *(float4*)(out + (size_t)row * D_ + c0 + 256) = o1;
}

// ---------------------------------------------------------------------------
extern "C" void kernel_launch(void* const* d_in, const int* in_sizes, int n_in,
                              void* d_out, int out_size, void* d_ws, size_t ws_size,
                              hipStream_t stream)
{
    const float* x  = (const float*)d_in[0];
    // d_in[1] = mask (causal, known statically) — unused
    const float* wq = (const float*)d_in[2];
    const float* bq = (const float*)d_in[3];
    const float* wk = (const float*)d_in[4];
    const float* bk = (const float*)d_in[5];
    const float* wv = (const float*)d_in[6];
    const float* bv = (const float*)d_in[7];
    const float* wo = (const float*)d_in[8];
    const float* bo = (const float*)d_in[9];
    const float* w1 = (const float*)d_in[10];
    const float* b1 = (const float*)d_in[11];
    const float* w2 = (const float*)d_in[12];
    const float* b2 = (const float*)d_in[13];
    const float* g1 = (const float*)d_in[14];
    const float* be1= (const float*)d_in[15];
    const float* g2 = (const float*)d_in[16];
    const float* be2= (const float*)d_in[17];
    float* out = (float*)d_out;

    // workspace layout (floats):
    //   [0, M*1536)           qkv  (dead after attention)
    //   [M*1536, M*2048)      ctx  (dead after out-proj)
    //   [0, M*2048)           ffn1 (reuses qkv+ctx region)
    //   [M*2048, M*2560)      attnout, later reused as ffn2 out
    //   [M*2560, M*3072)      h
    float* ws      = (float*)d_ws;
    float* qkv     = ws;
    float* ctx     = ws + (size_t)M_ * 1536;
    float* ffn1    = ws;
    float* attnout = ws + (size_t)M_ * 2048;
    float* h       = attnout + (size_t)M_ * 512;

    const dim3 blk(256);

    // QKV projections into interleaved [M,1536] buffer
    gemm_kernel<128,128,8,8,false><<<dim3(4,64), blk, 0, stream>>>(x, wq, 512, bq, qkv,        1536, 512);
    gemm_kernel<128,128,8,8,false><<<dim3(4,64), blk, 0, stream>>>(x, wk, 512, bk, qkv + 512,  1536, 512);
    gemm_kernel<128,128,8,8,false><<<dim3(4,64), blk, 0, stream>>>(x, wv, 512, bv, qkv + 1024, 1536, 512);

    // causal flash attention -> ctx [M,512]
    attn_kernel<<<dim3(32,32), blk, 0, stream>>>(qkv, ctx);

    // output projection
    gemm_kernel<64,64,4,4,false><<<dim3(8,128), blk, 0, stream>>>(ctx, wo, 512, bo, attnout, 512, 512);

    // h = LN(x + attnout)
    addln_kernel<<<dim3(M_/4), blk, 0, stream>>>(x, attnout, g1, be1, h);

    // ffn1 = relu(h @ w1 + b1)   [M, 2048]
    gemm_kernel<128,128,8,8,true><<<dim3(16,64), blk, 0, stream>>>(h, w1, 2048, b1, ffn1, 2048, 512);

    // ffn2 = ffn1 @ w2 + b2  -> reuse attnout buffer
    gemm_kernel<64,64,4,4,false><<<dim3(8,128), blk, 0, stream>>>(ffn1, w2, 512, b2, attnout, 512, 2048);

    // out = LN(h + ffn2)
    addln_kernel<<<dim3(M_/4), blk, 0, stream>>>(h, attnout, g2, be2, out);
}

// Round 3
// 388.226 us; speedup vs baseline: 4.0302x; 4.0302x over previous
//
#include <hip/hip_runtime.h>
#include <math.h>

#define D_   512
#define H_   8
#define DK_  64
#define FF_  2048
#define S_   2048
#define B_   4
#define M_   (B_*S_)     // 8192
#define EPS_ 1e-5f

typedef __attribute__((ext_vector_type(8))) short bf16x8;
typedef __attribute__((ext_vector_type(4))) float f32x4;

__device__ inline unsigned short f2b(float f) {
    unsigned u = __builtin_bit_cast(unsigned, f);
    unsigned r = (u + 0x7FFFu + ((u >> 16) & 1u)) >> 16;
    return (unsigned short)r;
}

// ---------------------------------------------------------------------------
// fp32 -> bf16 elementwise convert (x -> xb). n multiple of 2048.
// ---------------------------------------------------------------------------
__global__ __launch_bounds__(256)
void convert_bf16(const float* __restrict__ src, unsigned short* __restrict__ dst)
{
    const int i = (blockIdx.x * 256 + threadIdx.x) * 8;
    const float4 a = *(const float4*)(src + i);
    const float4 b = *(const float4*)(src + i + 4);
    bf16x8 v;
    v[0] = (short)f2b(a.x); v[1] = (short)f2b(a.y);
    v[2] = (short)f2b(a.z); v[3] = (short)f2b(a.w);
    v[4] = (short)f2b(b.x); v[5] = (short)f2b(b.y);
    v[6] = (short)f2b(b.z); v[7] = (short)f2b(b.w);
    *(bf16x8*)(dst + i) = v;
}

// ---------------------------------------------------------------------------
// Weight transpose+convert: w [K][N] f32 -> wt [N][K] bf16. 32x32 LDS tile.
// ---------------------------------------------------------------------------
__global__ __launch_bounds__(256)
void wtrans(const float* __restrict__ w, unsigned short* __restrict__ wt, int K, int N)
{
    __shared__ float L[32][33];
    const int k0 = blockIdx.y * 32, n0 = blockIdx.x * 32;
    const int x = threadIdx.x & 31, y = threadIdx.x >> 5;   // y 0..7
#pragma unroll
    for (int i = 0; i < 4; i++)
        L[y + i * 8][x] = w[(size_t)(k0 + y + i * 8) * N + n0 + x];
    __syncthreads();
#pragma unroll
    for (int i = 0; i < 4; i++)
        wt[(size_t)(n0 + y + i * 8) * K + k0 + x] = f2b(L[x][y + i * 8]);
}

// ---------------------------------------------------------------------------
// bf16 MFMA GEMM, 128x128 tile, BK=32, 4 waves (2x2), 64x64 per wave,
// 4x4 grid of 16x16x32 mfma. A [M][K] bf16, Bt [N][K] bf16 (pre-transposed).
// OUTB: 1 -> bf16 output, 0 -> fp32. RELU optional. ldc = row stride of C.
// ---------------------------------------------------------------------------
template<int OUTB, int RELU>
__global__ __launch_bounds__(256)
void gemm_bf16(const unsigned short* __restrict__ A, const unsigned short* __restrict__ Bt,
               const float* __restrict__ bias, void* __restrict__ Cv, int K, int ldc)
{
    constexpr int LDS = 40;                 // bf16 stride: 80 B rows, 16B-aligned, 2-way max
    __shared__ unsigned short As[128 * LDS];
    __shared__ unsigned short Bs[128 * LDS];

    const int tid  = threadIdx.x;
    const int lane = tid & 63;
    const int w    = tid >> 6;
    const int wr   = w >> 1, wc = w & 1;
    const int quad = lane >> 4;
    const int l15  = lane & 15;
    const int n0   = blockIdx.x * 128;
    const int m0   = blockIdx.y * 128;

    f32x4 acc[4][4];
#pragma unroll
    for (int i = 0; i < 4; i++)
#pragma unroll
        for (int j = 0; j < 4; j++) acc[i][j] = (f32x4){0.f, 0.f, 0.f, 0.f};

    for (int k0 = 0; k0 < K; k0 += 32) {
        __syncthreads();
#pragma unroll
        for (int i = 0; i < 2; i++) {       // 512 chunks of 8 bf16, 2/thread
            const int c = tid + i * 256;
            const int row = c >> 2, sub = (c & 3) * 8;
            *(bf16x8*)&As[row * LDS + sub] =
                *(const bf16x8*)&A[(size_t)(m0 + row) * K + k0 + sub];
            *(bf16x8*)&Bs[row * LDS + sub] =
                *(const bf16x8*)&Bt[(size_t)(n0 + row) * K + k0 + sub];
        }
        __syncthreads();

        bf16x8 af[4], bfr[4];
#pragma unroll
        for (int t = 0; t < 4; t++) {
            af[t]  = *(const bf16x8*)&As[(wr * 64 + t * 16 + l15) * LDS + quad * 8];
            bfr[t] = *(const bf16x8*)&Bs[(wc * 64 + t * 16 + l15) * LDS + quad * 8];
        }
#pragma unroll
        for (int mt = 0; mt < 4; mt++)
#pragma unroll
            for (int nt = 0; nt < 4; nt++)
                acc[mt][nt] = __builtin_amdgcn_mfma_f32_16x16x32_bf16(
                    af[mt], bfr[nt], acc[mt][nt], 0, 0, 0);
    }

    // epilogue: C/D layout col=lane&15, row=quad*4+reg  [verified m89/m91]
#pragma unroll
    for (int mt = 0; mt < 4; mt++) {
        const int rowb = m0 + wr * 64 + mt * 16 + quad * 4;
#pragma unroll
        for (int nt = 0; nt < 4; nt++) {
            const int col = n0 + wc * 64 + nt * 16 + l15;
            const float bv = bias[col];
#pragma unroll
            for (int r = 0; r < 4; r++) {
                float v = acc[mt][nt][r] + bv;
                if (RELU) v = fmaxf(v, 0.f);
                const size_t idx = (size_t)(rowb + r) * ldc + col;
                if (OUTB) ((unsigned short*)Cv)[idx] = f2b(v);
                else      ((float*)Cv)[idx] = v;
            }
        }
    }
}

// ---------------------------------------------------------------------------
// V transpose: qkv v-part [s][dk] per (b,h) -> vt [(b*8+h)*64+dk][s] bf16.
// ---------------------------------------------------------------------------
__global__ __launch_bounds__(256)
void vtrans(const unsigned short* __restrict__ qkv, unsigned short* __restrict__ vt)
{
    __shared__ unsigned short L[64][72];
    const int s0 = blockIdx.x * 64;
    const int bh = blockIdx.y;
    const int b  = bh >> 3, hh = bh & 7;
    const int tid = threadIdx.x;
    const unsigned short* src = qkv + (size_t)(b * S_) * 1536 + 1024 + hh * 64;
#pragma unroll
    for (int i = 0; i < 2; i++) {
        const int c = tid + i * 256;
        const int r = c >> 3, sub = (c & 7) * 8;
        *(bf16x8*)&L[r][sub] = *(const bf16x8*)(src + (size_t)(s0 + r) * 1536 + sub);
    }
    __syncthreads();
    const int dk = tid >> 2;
    const int sc = (tid & 3) * 16;
    bf16x8 t0, t1;
#pragma unroll
    for (int j = 0; j < 8; j++) t0[j] = (short)L[sc + j][dk];
#pragma unroll
    for (int j = 0; j < 8; j++) t1[j] = (short)L[sc + 8 + j][dk];
    unsigned short* dst = vt + (size_t)(bh * 64 + dk) * S_ + s0 + sc;
    *(bf16x8*)(dst)     = t0;
    *(bf16x8*)(dst + 8) = t1;
}

// ---------------------------------------------------------------------------
// Causal flash attention, bf16 MFMA. qkv [m][1536] = q|k|(v unused here),
// vt [(b*8+h)*64+dk][s]. ctx out bf16 [m][512].
// Block: 64 q-rows of one (b,h); 4 waves x 16 q-rows. 16 mfma per k-block.
// ---------------------------------------------------------------------------
__global__ __launch_bounds__(256)
void attn_mfma(const unsigned short* __restrict__ qkv,
               const unsigned short* __restrict__ vt,
               unsigned short* __restrict__ ctx)
{
    constexpr int LDK = 72;                 // 144 B rows: 16B-aligned, 2-way max
    __shared__ unsigned short Ks[64 * LDK];
    __shared__ unsigned short Vs[64 * LDK]; // V^T tile [dk][kr]
    __shared__ unsigned short Ps[4][16 * LDK];

    const int tid  = threadIdx.x;
    const int lane = tid & 63;
    const int w    = tid >> 6;
    const int quad = lane >> 4;
    const int l15  = lane & 15;
    const int qb   = 31 - (int)blockIdx.x;  // heavy blocks first
    const int bh   = blockIdx.y;
    const int b    = bh >> 3, hh = bh & 7;

    const unsigned short* qbase = qkv + (size_t)(b * S_) * 1536 + hh * 64;
    const unsigned short* kbase = qbase + 512;
    const unsigned short* vtb   = vt + (size_t)bh * 64 * S_;

    // Q fragments (A layout: m=lane&15, k=quad*8+j), d = 64 -> 2 chunks
    bf16x8 qf[2];
    {
        const unsigned short* qr = qbase + (size_t)(qb * 64 + w * 16 + l15) * 1536;
        qf[0] = *(const bf16x8*)(qr + quad * 8);
        qf[1] = *(const bf16x8*)(qr + 32 + quad * 8);
    }

    f32x4 Oacc[4];
#pragma unroll
    for (int i = 0; i < 4; i++) Oacc[i] = (f32x4){0.f, 0.f, 0.f, 0.f};
    float mrow[4], lrow[4];
#pragma unroll
    for (int r = 0; r < 4; r++) { mrow[r] = -INFINITY; lrow[r] = 0.f; }

    for (int kb = 0; kb <= qb; kb++) {
        __syncthreads();
        // stage K tile [kr][d] and V^T tile [dk][kr]
#pragma unroll
        for (int i = 0; i < 2; i++) {
            const int c = tid + i * 256;
            const int row = c >> 3, sub = (c & 7) * 8;
            *(bf16x8*)&Ks[row * LDK + sub] =
                *(const bf16x8*)(kbase + (size_t)(kb * 64 + row) * 1536 + sub);
            *(bf16x8*)&Vs[row * LDK + sub] =
                *(const bf16x8*)(vtb + (size_t)row * S_ + kb * 64 + sub);
        }
        __syncthreads();

        // S = Q @ K^T  (B operand = K rows, k-major)
        f32x4 sacc[4];
#pragma unroll
        for (int nt = 0; nt < 4; nt++) sacc[nt] = (f32x4){0.f, 0.f, 0.f, 0.f};
#pragma unroll
        for (int kc = 0; kc < 2; kc++)
#pragma unroll
            for (int nt = 0; nt < 4; nt++) {
                const bf16x8 kf = *(const bf16x8*)&Ks[(nt * 16 + l15) * LDK + kc * 32 + quad * 8];
                sacc[nt] = __builtin_amdgcn_mfma_f32_16x16x32_bf16(qf[kc], kf, sacc[nt], 0, 0, 0);
            }

        // scale + causal mask + online softmax (C layout rows quad*4+r)
        const int qg0 = qb * 64 + w * 16 + quad * 4;
        const bool diag = (kb == qb);
        float pr[4][4], alpha[4];
#pragma unroll
        for (int r = 0; r < 4; r++) {
            float sv[4];
#pragma unroll
            for (int nt = 0; nt < 4; nt++) {
                float s = sacc[nt][r] * 0.125f;
                if (diag) {
                    const int kg = kb * 64 + nt * 16 + l15;
                    if (kg > qg0 + r) s = -1.0e9f;
                }
                sv[nt] = s;
            }
            float rmax = fmaxf(fmaxf(sv[0], sv[1]), fmaxf(sv[2], sv[3]));
#pragma unroll
            for (int m = 1; m < 16; m <<= 1) rmax = fmaxf(rmax, __shfl_xor(rmax, m));
            const float mnew = fmaxf(mrow[r], rmax);
            const float al = __expf(mrow[r] - mnew);
            float rsum = 0.f;
#pragma unroll
            for (int nt = 0; nt < 4; nt++) { sv[nt] = __expf(sv[nt] - mnew); rsum += sv[nt]; }
#pragma unroll
            for (int m = 1; m < 16; m <<= 1) rsum += __shfl_xor(rsum, m);
            lrow[r] = lrow[r] * al + rsum;
            mrow[r] = mnew;
            alpha[r] = al;
#pragma unroll
            for (int nt = 0; nt < 4; nt++) pr[nt][r] = sv[nt];
        }
#pragma unroll
        for (int nt = 0; nt < 4; nt++)
#pragma unroll
            for (int r = 0; r < 4; r++) Oacc[nt][r] *= alpha[r];

        // P (C layout) -> per-wave LDS in A layout rows [q][kr]
        unsigned short* pw = &Ps[w][0];
#pragma unroll
        for (int nt = 0; nt < 4; nt++)
#pragma unroll
            for (int r = 0; r < 4; r++)
                pw[(quad * 4 + r) * LDK + nt * 16 + l15] = f2b(pr[nt][r]);
        // intra-wave RAW on LDS: compiler inserts lgkmcnt waits; no barrier needed

        // O += P @ V   (A = P rows k-major over kr; B = V^T rows [dk][kr])
#pragma unroll
        for (int kc = 0; kc < 2; kc++) {
            const bf16x8 af = *(const bf16x8*)&pw[l15 * LDK + kc * 32 + quad * 8];
#pragma unroll
            for (int nt = 0; nt < 4; nt++) {
                const bf16x8 vf = *(const bf16x8*)&Vs[(nt * 16 + l15) * LDK + kc * 32 + quad * 8];
                Oacc[nt] = __builtin_amdgcn_mfma_f32_16x16x32_bf16(af, vf, Oacc[nt], 0, 0, 0);
            }
        }
    }

    // epilogue: normalize, write ctx bf16
    const int orow = qb * 64 + w * 16 + quad * 4;
    unsigned short* cb = ctx + (size_t)(b * S_) * 512 + hh * 64;
#pragma unroll
    for (int r = 0; r < 4; r++) {
        const float inv = 1.f / lrow[r];
#pragma unroll
        for (int nt = 0; nt < 4; nt++)
            cb[(size_t)(orow + r) * 512 + nt * 16 + l15] = f2b(Oacc[nt][r] * inv);
    }
}

// ---------------------------------------------------------------------------
// out = LayerNorm(a + r) * g + be; optionally also bf16 copy. 1 wave/row.
// ---------------------------------------------------------------------------
template<int WB>
__global__ __launch_bounds__(256)
void addln_kernel(const float* __restrict__ a, const float* __restrict__ r,
                  const float* __restrict__ g, const float* __restrict__ be,
                  float* __restrict__ out, unsigned short* __restrict__ outb)
{
    const int wave = threadIdx.x >> 6;
    const int lane = threadIdx.x & 63;
    const int row  = blockIdx.x * 4 + wave;
    const float* pa = a + (size_t)row * D_;
    const float* pr = r + (size_t)row * D_;
    const int c0 = lane * 4;

    float v[8];
    {
        const float4 a0 = *(const float4*)(pa + c0);
        const float4 r0 = *(const float4*)(pr + c0);
        v[0] = a0.x + r0.x; v[1] = a0.y + r0.y; v[2] = a0.z + r0.z; v[3] = a0.w + r0.w;
        const float4 a1 = *(const float4*)(pa + c0 + 256);
        const float4 r1 = *(const float4*)(pr + c0 + 256);
        v[4] = a1.x + r1.x; v[5] = a1.y + r1.y; v[6] = a1.z + r1.z; v[7] = a1.w + r1.w;
    }

    float sum = 0.f;
#pragma unroll
    for (int i = 0; i < 8; i++) sum += v[i];
#pragma unroll
    for (int m = 1; m < 64; m <<= 1) sum += __shfl_xor(sum, m);
    const float mu = sum * (1.f / D_);

    float sq = 0.f;
#pragma unroll
    for (int i = 0; i < 8; i++) { const float d = v[i] - mu; sq += d * d; }
#pragma unroll
    for (int m = 1; m < 64; m <<= 1) sq += __shfl_xor(sq, m);
    const float rstd = rsqrtf(sq * (1.f / D_) + EPS_);

    const float4 g0 = *(const float4*)(g + c0);
    const float4 b0 = *(const float4*)(be + c0);
    const float4 g1 = *(const float4*)(g + c0 + 256);
    const float4 b1 = *(const float4*)(be + c0 + 256);

    float o[8];
    o[0] = (v[0] - mu) * rstd * g0.x + b0.x;
    o[1] = (v[1] - mu) * rstd * g0.y + b0.y;
    o[2] = (v[2] - mu) * rstd * g0.z + b0.z;
    o[3] = (v[3] - mu) * rstd * g0.w + b0.w;
    o[4] = (v[4] - mu) * rstd * g1.x + b1.x;
    o[5] = (v[5] - mu) * rstd * g1.y + b1.y;
    o[6] = (v[6] - mu) * rstd * g1.z + b1.z;
    o[7] = (v[7] - mu) * rstd * g1.w + b1.w;

    *(float4*)(out + (size_t)row * D_ + c0)       = *(float4*)&o[0];
    *(float4*)(out + (size_t)row * D_ + c0 + 256) = *(float4*)&o[4];
    if (WB) {
        bf16x8 vb;
#pragma unroll
        for (int i = 0; i < 4; i++) vb[i] = (short)f2b(o[i]);
        bf16x8 vb2;
#pragma unroll
        for (int i = 0; i < 4; i++) vb2[i] = (short)f2b(o[4 + i]);
        // pack 4+4 into two 8B stores (keep layout simple: two ushort4 stores)
        *(short4*)(outb + (size_t)row * D_ + c0) = (short4){vb[0], vb[1], vb[2], vb[3]};
        *(short4*)(outb + (size_t)row * D_ + c0 + 256) = (short4){vb2[0], vb2[1], vb2[2], vb2[3]};
    }
}

// ---------------------------------------------------------------------------
extern "C" void kernel_launch(void* const* d_in, const int* in_sizes, int n_in,
                              void* d_out, int out_size, void* d_ws, size_t ws_size,
                              hipStream_t stream)
{
    const float* x  = (const float*)d_in[0];
    const float* wq = (const float*)d_in[2];
    const float* bq = (const float*)d_in[3];
    const float* wk = (const float*)d_in[4];
    const float* bk = (const float*)d_in[5];
    const float* wv = (const float*)d_in[6];
    const float* bv = (const float*)d_in[7];
    const float* wo = (const float*)d_in[8];
    const float* bo = (const float*)d_in[9];
    const float* w1 = (const float*)d_in[10];
    const float* b1 = (const float*)d_in[11];
    const float* w2 = (const float*)d_in[12];
    const float* b2 = (const float*)d_in[13];
    const float* g1 = (const float*)d_in[14];
    const float* be1= (const float*)d_in[15];
    const float* g2 = (const float*)d_in[16];
    const float* be2= (const float*)d_in[17];
    float* out = (float*)d_out;

    // workspace layout (bytes), peak 88 MB (round-0 used 100.7 MB -> fits):
    const size_t MB = 1048576;
    char* w8 = (char*)d_ws;
    unsigned short* wqkvt = (unsigned short*)(w8 + 0);            // 1536x512 bf16
    unsigned short* wot   = (unsigned short*)(w8 + 1572864);      // 512x512
    unsigned short* w1t   = (unsigned short*)(w8 + 2097152);      // 2048x512
    unsigned short* w2t   = (unsigned short*)(w8 + 4194304);      // 512x2048
    float*          bqkv  = (float*)(w8 + 6291456);               // 1536 f32
    unsigned short* qkv   = (unsigned short*)(w8 + 8 * MB);       // 24 MB  (later ffn1b 32 MB)
    unsigned short* ffn1b = qkv;
    unsigned short* xb    = (unsigned short*)(w8 + 40 * MB);      // 8 MB   (later ctx)
    unsigned short* ctx   = xb;
    unsigned short* vt    = (unsigned short*)(w8 + 48 * MB);      // 8 MB   (later hb)
    unsigned short* hb    = vt;
    float*          attnout = (float*)(w8 + 56 * MB);             // 16 MB  (later ffn2)
    float*          ffn2  = attnout;
    float*          h     = (float*)(w8 + 72 * MB);               // 16 MB

    const dim3 blk(256);

    // --- conversions / transposes (once per launch; ~6 MB of weights)
    convert_bf16<<<dim3(M_ * D_ / 8 / 256), blk, 0, stream>>>(x, xb);
    wtrans<<<dim3(16, 16), blk, 0, stream>>>(wq, wqkvt, 512, 512);
    wtrans<<<dim3(16, 16), blk, 0, stream>>>(wk, wqkvt + 512 * 512, 512, 512);
    wtrans<<<dim3(16, 16), blk, 0, stream>>>(wv, wqkvt + 1024 * 512, 512, 512);
    wtrans<<<dim3(16, 16), blk, 0, stream>>>(wo, wot, 512, 512);
    wtrans<<<dim3(64, 16), blk, 0, stream>>>(w1, w1t, 512, 2048);
    wtrans<<<dim3(16, 64), blk, 0, stream>>>(w2, w2t, 2048, 512);
    hipMemcpyAsync(bqkv,        bq, 512 * 4, hipMemcpyDeviceToDevice, stream);
    hipMemcpyAsync(bqkv + 512,  bk, 512 * 4, hipMemcpyDeviceToDevice, stream);
    hipMemcpyAsync(bqkv + 1024, bv, 512 * 4, hipMemcpyDeviceToDevice, stream);

    // --- qkv = xb @ [wq|wk|wv] + b  -> bf16 [M][1536]
    gemm_bf16<1, 0><<<dim3(12, 64), blk, 0, stream>>>(xb, wqkvt, bqkv, qkv, 512, 1536);

    // --- v transpose -> vt [(b*8+h)*64+dk][s]
    vtrans<<<dim3(32, 32), blk, 0, stream>>>(qkv, vt);

    // --- causal flash attention (MFMA) -> ctx bf16 [M][512]
    attn_mfma<<<dim3(32, 32), blk, 0, stream>>>(qkv, vt, ctx);

    // --- attnout = ctx @ wo + bo (fp32)
    gemm_bf16<0, 0><<<dim3(4, 64), blk, 0, stream>>>(ctx, wot, bo, attnout, 512, 512);

    // --- h = LN(x + attnout) (fp32 + bf16 copy)
    addln_kernel<1><<<dim3(M_ / 4), blk, 0, stream>>>(x, attnout, g1, be1, h, hb);

    // --- ffn1 = relu(hb @ w1 + b1) -> bf16 [M][2048]
    gemm_bf16<1, 1><<<dim3(16, 64), blk, 0, stream>>>(hb, w1t, b1, ffn1b, 512, 2048);

    // --- ffn2 = ffn1 @ w2 + b2 (fp32)
    gemm_bf16<0, 0><<<dim3(4, 64), blk, 0, stream>>>(ffn1b, w2t, b2, ffn2, 2048, 512);

    // --- out = LN(h + ffn2)
    addln_kernel<0><<<dim3(M_ / 4), blk, 0, stream>>>(h, ffn2, g2, be2, out, nullptr);
}

// Round 4
// 324.757 us; speedup vs baseline: 4.8179x; 1.1954x over previous
//
#include <hip/hip_runtime.h>
#include <math.h>

#define D_   512
#define H_   8
#define DK_  64
#define FF_  2048
#define S_   2048
#define B_   4
#define M_   (B_*S_)     // 8192
#define EPS_ 1e-5f

typedef __attribute__((ext_vector_type(8))) short bf16x8;
typedef __attribute__((ext_vector_type(4))) float f32x4;

__device__ inline unsigned short f2b(float f) {
    unsigned u = __builtin_bit_cast(unsigned, f);
    unsigned r = (u + 0x7FFFu + ((u >> 16) & 1u)) >> 16;
    return (unsigned short)r;
}

// async 16B global->LDS (m97 pattern). LDS dest must be wave-uniform base +
// lane*16 — callers arrange chunk ids so lanes are contiguous.
__device__ __forceinline__ void async_cp16(const void* g, void* l) {
    __builtin_amdgcn_global_load_lds(
        (const __attribute__((address_space(1))) unsigned int*)g,
        (__attribute__((address_space(3))) unsigned int*)l, 16, 0, 0);
}

// ---------------------------------------------------------------------------
// fp32 -> bf16 elementwise convert.
// ---------------------------------------------------------------------------
__global__ __launch_bounds__(256)
void convert_bf16(const float* __restrict__ src, unsigned short* __restrict__ dst)
{
    const int i = (blockIdx.x * 256 + threadIdx.x) * 8;
    const float4 a = *(const float4*)(src + i);
    const float4 b = *(const float4*)(src + i + 4);
    bf16x8 v;
    v[0] = (short)f2b(a.x); v[1] = (short)f2b(a.y);
    v[2] = (short)f2b(a.z); v[3] = (short)f2b(a.w);
    v[4] = (short)f2b(b.x); v[5] = (short)f2b(b.y);
    v[6] = (short)f2b(b.z); v[7] = (short)f2b(b.w);
    *(bf16x8*)(dst + i) = v;
}

// ---------------------------------------------------------------------------
// Weight transpose+convert: w [K][N] f32 -> wt [N][K] bf16.
// ---------------------------------------------------------------------------
__global__ __launch_bounds__(256)
void wtrans(const float* __restrict__ w, unsigned short* __restrict__ wt, int K, int N)
{
    __shared__ float L[32][33];
    const int k0 = blockIdx.y * 32, n0 = blockIdx.x * 32;
    const int x = threadIdx.x & 31, y = threadIdx.x >> 5;
#pragma unroll
    for (int i = 0; i < 4; i++)
        L[y + i * 8][x] = w[(size_t)(k0 + y + i * 8) * N + n0 + x];
    __syncthreads();
#pragma unroll
    for (int i = 0; i < 4; i++)
        wt[(size_t)(n0 + y + i * 8) * K + k0 + x] = f2b(L[x][y + i * 8]);
}

// ---------------------------------------------------------------------------
// bf16 MFMA GEMM, m97 structure: unpadded LDS, global_load_lds staging.
// Tile BM x BN (BM=WR*MT*16, BN=WC*NT*16), BK=32, 4 waves.
// A [M][K] bf16, Bt [N][K] bf16. OUTB: bf16 out else fp32. ldc = C row stride.
// ---------------------------------------------------------------------------
template<int WR, int WC, int MT, int NT, int OUTB, int RELU>
__global__ __launch_bounds__(256)
void gemm_bf16(const unsigned short* __restrict__ A, const unsigned short* __restrict__ Bt,
               const float* __restrict__ bias, void* __restrict__ Cv, int K, int ldc)
{
    constexpr int BM = WR * MT * 16;
    constexpr int BN = WC * NT * 16;
    __shared__ unsigned short As[BM * 32];
    __shared__ unsigned short Bs[BN * 32];

    const int tid  = threadIdx.x;
    const int lane = tid & 63;
    const int w    = tid >> 6;
    const int wr   = w / WC, wc = w % WC;
    const int quad = lane >> 4;
    const int l15  = lane & 15;
    const int n0   = blockIdx.x * BN;
    const int m0   = blockIdx.y * BM;

    f32x4 acc[MT][NT];
#pragma unroll
    for (int i = 0; i < MT; i++)
#pragma unroll
        for (int j = 0; j < NT; j++) acc[i][j] = (f32x4){0.f, 0.f, 0.f, 0.f};

    constexpr int CA = BM / 64;   // 16B chunks per thread (A): BM*4/256
    constexpr int CB = BN / 64;

    for (int k0 = 0; k0 < K; k0 += 32) {
        __syncthreads();
#pragma unroll
        for (int i = 0; i < CA; i++) {
            const int c = tid + i * 256;          // lanes contiguous per wave
            async_cp16(&A[(size_t)(m0 + (c >> 2)) * K + k0 + (c & 3) * 8], &As[c * 8]);
        }
#pragma unroll
        for (int i = 0; i < CB; i++) {
            const int c = tid + i * 256;
            async_cp16(&Bt[(size_t)(n0 + (c >> 2)) * K + k0 + (c & 3) * 8], &Bs[c * 8]);
        }
        __builtin_amdgcn_s_waitcnt(0x0f70);       // vmcnt(0)
        __syncthreads();

        bf16x8 af[MT], bfr[NT];
#pragma unroll
        for (int t = 0; t < MT; t++)
            af[t]  = *(const bf16x8*)&As[(wr * MT * 16 + t * 16 + l15) * 32 + quad * 8];
#pragma unroll
        for (int t = 0; t < NT; t++)
            bfr[t] = *(const bf16x8*)&Bs[(wc * NT * 16 + t * 16 + l15) * 32 + quad * 8];
#pragma unroll
        for (int mt = 0; mt < MT; mt++)
#pragma unroll
            for (int nt = 0; nt < NT; nt++)
                acc[mt][nt] = __builtin_amdgcn_mfma_f32_16x16x32_bf16(
                    af[mt], bfr[nt], acc[mt][nt], 0, 0, 0);
    }

    // epilogue: C/D layout col=lane&15, row=quad*4+reg
#pragma unroll
    for (int mt = 0; mt < MT; mt++) {
        const int rowb = m0 + wr * MT * 16 + mt * 16 + quad * 4;
#pragma unroll
        for (int nt = 0; nt < NT; nt++) {
            const int col = n0 + wc * NT * 16 + nt * 16 + l15;
            const float bv = bias[col];
#pragma unroll
            for (int r = 0; r < 4; r++) {
                float v = acc[mt][nt][r] + bv;
                if (RELU) v = fmaxf(v, 0.f);
                const size_t idx = (size_t)(rowb + r) * ldc + col;
                if (OUTB) ((unsigned short*)Cv)[idx] = f2b(v);
                else      ((float*)Cv)[idx] = v;
            }
        }
    }
}

// ---------------------------------------------------------------------------
// V transpose: qkv v-part [s][dk] per (b,h) -> vt [(b*8+h)*64+dk][s] bf16.
// ---------------------------------------------------------------------------
__global__ __launch_bounds__(256)
void vtrans(const unsigned short* __restrict__ qkv, unsigned short* __restrict__ vt)
{
    __shared__ unsigned short L[64][72];
    const int s0 = blockIdx.x * 64;
    const int bh = blockIdx.y;
    const int b  = bh >> 3, hh = bh & 7;
    const int tid = threadIdx.x;
    const unsigned short* src = qkv + (size_t)(b * S_) * 1536 + 1024 + hh * 64;
#pragma unroll
    for (int i = 0; i < 2; i++) {
        const int c = tid + i * 256;
        const int r = c >> 3, sub = (c & 7) * 8;
        *(bf16x8*)&L[r][sub] = *(const bf16x8*)(src + (size_t)(s0 + r) * 1536 + sub);
    }
    __syncthreads();
    const int dk = tid >> 2;
    const int sc = (tid & 3) * 16;
    bf16x8 t0, t1;
#pragma unroll
    for (int j = 0; j < 8; j++) t0[j] = (short)L[sc + j][dk];
#pragma unroll
    for (int j = 0; j < 8; j++) t1[j] = (short)L[sc + 8 + j][dk];
    unsigned short* dst = vt + (size_t)(bh * 64 + dk) * S_ + s0 + sc;
    *(bf16x8*)(dst)     = t0;
    *(bf16x8*)(dst + 8) = t1;
}

// ---------------------------------------------------------------------------
// Causal flash attention, bf16 MFMA. BQ=64 (4 waves x 16 q-rows), KB=128.
// K/V tiles: unpadded LDS, XOR-swizzled chunks, async global_load_lds staging.
// qkv [m][1536] = q|k|v; vt [(b*8+h)*64+dk][s]; ctx out bf16 [m][512].
// 1D LPT grid: heaviest qb first across all (b,h).
// ---------------------------------------------------------------------------
__global__ __launch_bounds__(256)
void attn_mfma(const unsigned short* __restrict__ qkv,
               const unsigned short* __restrict__ vt,
               unsigned short* __restrict__ ctx)
{
    constexpr int LDP = 136;                 // P row stride (272B: 16B-aligned)
    __shared__ unsigned short Ks[128 * 64];  // [kr][d], chunk^=(kr&7) swizzle
    __shared__ unsigned short Vs[64 * 128];  // [dk][kr], chunk^=(dk&15) swizzle
    __shared__ unsigned short Ps[4][16 * LDP];

    const int tid  = threadIdx.x;
    const int lane = tid & 63;
    const int w    = tid >> 6;
    const int quad = lane >> 4;
    const int l15  = lane & 15;
    const int bid  = blockIdx.x;
    const int qb   = 31 - (bid >> 5);        // LPT: qb=31 blocks dispatch first
    const int bh   = bid & 31;
    const int b    = bh >> 3, hh = bh & 7;

    const unsigned short* qbase = qkv + (size_t)(b * S_) * 1536 + hh * 64;
    const unsigned short* kbase = qbase + 512;
    const unsigned short* vtb   = vt + (size_t)bh * 64 * S_;

    // Q fragments (A layout: m=lane&15, k=quad*8+j), d=64 -> 2 chunks
    bf16x8 qf[2];
    {
        const unsigned short* qr = qbase + (size_t)(qb * 64 + w * 16 + l15) * 1536;
        qf[0] = *(const bf16x8*)(qr + quad * 8);
        qf[1] = *(const bf16x8*)(qr + 32 + quad * 8);
    }

    f32x4 Oacc[4];
#pragma unroll
    for (int i = 0; i < 4; i++) Oacc[i] = (f32x4){0.f, 0.f, 0.f, 0.f};
    float mrow[4], lrow[4];
#pragma unroll
    for (int r = 0; r < 4; r++) { mrow[r] = -INFINITY; lrow[r] = 0.f; }

    const float SCL = 0.125f * 1.44269504089f;   // 1/sqrt(64) * log2(e)
    const int   qg0 = qb * 64 + w * 16 + quad * 4;
    const int   klim = qb * 64 + w * 16 + 15;    // wave's max q row
    const int   nkb  = (qb >> 1) + 1;
    unsigned short* pw = &Ps[w][0];

    for (int kb = 0; kb < nkb; kb++) {
        __syncthreads();
        // ---- stage K tile [128 kr][64 d] (swizzled) via async cp
#pragma unroll
        for (int i = 0; i < 4; i++) {
            const int c = tid + i * 256;
            const int row = c >> 3;
            const int l = (c & 7) ^ (row & 7);
            async_cp16(kbase + (size_t)(kb * 128 + row) * 1536 + l * 8, &Ks[c * 8]);
        }
        // ---- stage V^T tile [64 dk][128 kr] (swizzled)
#pragma unroll
        for (int i = 0; i < 4; i++) {
            const int c = tid + i * 256;
            const int row = c >> 4;
            const int l = (c & 15) ^ (row & 15);
            async_cp16(vtb + (size_t)row * S_ + kb * 128 + l * 8, &Vs[c * 8]);
        }
        __builtin_amdgcn_s_waitcnt(0x0f70);      // vmcnt(0)
        __syncthreads();

        const bool diag = (kb == nkb - 1);

        // ---- S = Q @ K^T over 8 k-column tiles (skip fully-masked tiles)
        f32x4 sacc[8];
#pragma unroll
        for (int nt = 0; nt < 8; nt++) sacc[nt] = (f32x4){0.f, 0.f, 0.f, 0.f};
#pragma unroll
        for (int nt = 0; nt < 8; nt++) {
            if (diag && (kb * 128 + nt * 16 > klim)) continue;
#pragma unroll
            for (int kc = 0; kc < 2; kc++) {
                const int phys = (kc * 4 + quad) ^ (l15 & 7);
                const bf16x8 kf = *(const bf16x8*)&Ks[(nt * 16 + l15) * 64 + phys * 8];
                sacc[nt] = __builtin_amdgcn_mfma_f32_16x16x32_bf16(qf[kc], kf, sacc[nt], 0, 0, 0);
            }
        }

        // ---- online softmax (exp2 domain), write P tile (per-wave LDS)
        float alpha[4];
#pragma unroll
        for (int r = 0; r < 4; r++) {
            float sv[8];
#pragma unroll
            for (int nt = 0; nt < 8; nt++) {
                float s = sacc[nt][r] * SCL;
                if (diag) {
                    const int kg = kb * 128 + nt * 16 + l15;
                    if (kg > qg0 + r) s = -3.0e8f;
                }
                sv[nt] = s;
            }
            float m0 = fmaxf(fmaxf(sv[0], sv[1]), fmaxf(sv[2], sv[3]));
            float m1 = fmaxf(fmaxf(sv[4], sv[5]), fmaxf(sv[6], sv[7]));
            float rmax = fmaxf(m0, m1);
#pragma unroll
            for (int m = 1; m < 16; m <<= 1) rmax = fmaxf(rmax, __shfl_xor(rmax, m));
            const float mnew = fmaxf(mrow[r], rmax);
            alpha[r] = exp2f(mrow[r] - mnew);
            float rsum = 0.f;
#pragma unroll
            for (int nt = 0; nt < 8; nt++) {
                sv[nt] = exp2f(sv[nt] - mnew);
                rsum += sv[nt];
            }
#pragma unroll
            for (int m = 1; m < 16; m <<= 1) rsum += __shfl_xor(rsum, m);
            lrow[r] = lrow[r] * alpha[r] + rsum;
            mrow[r] = mnew;
#pragma unroll
            for (int nt = 0; nt < 8; nt++)
                pw[(quad * 4 + r) * LDP + nt * 16 + l15] = f2b(sv[nt]);
        }
#pragma unroll
        for (int nt = 0; nt < 4; nt++)
#pragma unroll
            for (int r = 0; r < 4; r++) Oacc[nt][r] *= alpha[r];

        // ---- O += P @ V  (A = P [q][k]; B = V^T [dk][k]); intra-wave LDS RAW
#pragma unroll
        for (int kc = 0; kc < 4; kc++) {
            const bf16x8 af = *(const bf16x8*)&pw[l15 * LDP + kc * 32 + quad * 8];
#pragma unroll
            for (int nt = 0; nt < 4; nt++) {
                const int phys = (kc * 4 + quad) ^ l15;
                const bf16x8 vf = *(const bf16x8*)&Vs[(nt * 16 + l15) * 128 + phys * 8];
                Oacc[nt] = __builtin_amdgcn_mfma_f32_16x16x32_bf16(af, vf, Oacc[nt], 0, 0, 0);
            }
        }
    }

    // ---- normalize + write ctx bf16
    const int orow = qb * 64 + w * 16 + quad * 4;
    unsigned short* cb = ctx + (size_t)(b * S_) * 512 + hh * 64;
#pragma unroll
    for (int r = 0; r < 4; r++) {
        const float inv = 1.f / lrow[r];
#pragma unroll
        for (int nt = 0; nt < 4; nt++)
            cb[(size_t)(orow + r) * 512 + nt * 16 + l15] = f2b(Oacc[nt][r] * inv);
    }
}

// ---------------------------------------------------------------------------
// out = LayerNorm(a + r) * g + be; optionally also bf16 copy. 1 wave/row.
// ---------------------------------------------------------------------------
template<int WB>
__global__ __launch_bounds__(256)
void addln_kernel(const float* __restrict__ a, const float* __restrict__ r,
                  const float* __restrict__ g, const float* __restrict__ be,
                  float* __restrict__ out, unsigned short* __restrict__ outb)
{
    const int wave = threadIdx.x >> 6;
    const int lane = threadIdx.x & 63;
    const int row  = blockIdx.x * 4 + wave;
    const float* pa = a + (size_t)row * D_;
    const float* pr = r + (size_t)row * D_;
    const int c0 = lane * 4;

    float v[8];
    {
        const float4 a0 = *(const float4*)(pa + c0);
        const float4 r0 = *(const float4*)(pr + c0);
        v[0] = a0.x + r0.x; v[1] = a0.y + r0.y; v[2] = a0.z + r0.z; v[3] = a0.w + r0.w;
        const float4 a1 = *(const float4*)(pa + c0 + 256);
        const float4 r1 = *(const float4*)(pr + c0 + 256);
        v[4] = a1.x + r1.x; v[5] = a1.y + r1.y; v[6] = a1.z + r1.z; v[7] = a1.w + r1.w;
    }

    float sum = 0.f;
#pragma unroll
    for (int i = 0; i < 8; i++) sum += v[i];
#pragma unroll
    for (int m = 1; m < 64; m <<= 1) sum += __shfl_xor(sum, m);
    const float mu = sum * (1.f / D_);

    float sq = 0.f;
#pragma unroll
    for (int i = 0; i < 8; i++) { const float d = v[i] - mu; sq += d * d; }
#pragma unroll
    for (int m = 1; m < 64; m <<= 1) sq += __shfl_xor(sq, m);
    const float rstd = rsqrtf(sq * (1.f / D_) + EPS_);

    const float4 g0 = *(const float4*)(g + c0);
    const float4 b0 = *(const float4*)(be + c0);
    const float4 g1 = *(const float4*)(g + c0 + 256);
    const float4 b1 = *(const float4*)(be + c0 + 256);

    float o[8];
    o[0] = (v[0] - mu) * rstd * g0.x + b0.x;
    o[1] = (v[1] - mu) * rstd * g0.y + b0.y;
    o[2] = (v[2] - mu) * rstd * g0.z + b0.z;
    o[3] = (v[3] - mu) * rstd * g0.w + b0.w;
    o[4] = (v[4] - mu) * rstd * g1.x + b1.x;
    o[5] = (v[5] - mu) * rstd * g1.y + b1.y;
    o[6] = (v[6] - mu) * rstd * g1.z + b1.z;
    o[7] = (v[7] - mu) * rstd * g1.w + b1.w;

    *(float4*)(out + (size_t)row * D_ + c0)       = *(float4*)&o[0];
    *(float4*)(out + (size_t)row * D_ + c0 + 256) = *(float4*)&o[4];
    if (WB) {
        short4 vb0 = (short4){(short)f2b(o[0]), (short)f2b(o[1]), (short)f2b(o[2]), (short)f2b(o[3])};
        short4 vb1 = (short4){(short)f2b(o[4]), (short)f2b(o[5]), (short)f2b(o[6]), (short)f2b(o[7])};
        *(short4*)(outb + (size_t)row * D_ + c0)       = vb0;
        *(short4*)(outb + (size_t)row * D_ + c0 + 256) = vb1;
    }
}

// ---------------------------------------------------------------------------
extern "C" void kernel_launch(void* const* d_in, const int* in_sizes, int n_in,
                              void* d_out, int out_size, void* d_ws, size_t ws_size,
                              hipStream_t stream)
{
    const float* x  = (const float*)d_in[0];
    const float* wq = (const float*)d_in[2];
    const float* bq = (const float*)d_in[3];
    const float* wk = (const float*)d_in[4];
    const float* bk = (const float*)d_in[5];
    const float* wv = (const float*)d_in[6];
    const float* bv = (const float*)d_in[7];
    const float* wo = (const float*)d_in[8];
    const float* bo = (const float*)d_in[9];
    const float* w1 = (const float*)d_in[10];
    const float* b1 = (const float*)d_in[11];
    const float* w2 = (const float*)d_in[12];
    const float* b2 = (const float*)d_in[13];
    const float* g1 = (const float*)d_in[14];
    const float* be1= (const float*)d_in[15];
    const float* g2 = (const float*)d_in[16];
    const float* be2= (const float*)d_in[17];
    float* out = (float*)d_out;

    const size_t MB = 1048576;
    char* w8 = (char*)d_ws;
    unsigned short* wqkvt = (unsigned short*)(w8 + 0);            // 1536x512 bf16
    unsigned short* wot   = (unsigned short*)(w8 + 1572864);      // 512x512
    unsigned short* w1t   = (unsigned short*)(w8 + 2097152);      // 2048x512
    unsigned short* w2t   = (unsigned short*)(w8 + 4194304);      // 512x2048
    float*          bqkv  = (float*)(w8 + 6291456);               // 1536 f32
    unsigned short* qkv   = (unsigned short*)(w8 + 8 * MB);       // 24 MB (later ffn1b)
    unsigned short* ffn1b = qkv;
    unsigned short* xb    = (unsigned short*)(w8 + 40 * MB);      // 8 MB (later ctx)
    unsigned short* ctx   = xb;
    unsigned short* vt    = (unsigned short*)(w8 + 48 * MB);      // 8 MB (later hb)
    unsigned short* hb    = vt;
    float*          attnout = (float*)(w8 + 56 * MB);             // 16 MB (later ffn2)
    float*          ffn2  = attnout;
    float*          h     = (float*)(w8 + 72 * MB);               // 16 MB

    const dim3 blk(256);

    // --- conversions / transposes
    convert_bf16<<<dim3(M_ * D_ / 8 / 256), blk, 0, stream>>>(x, xb);
    wtrans<<<dim3(16, 16), blk, 0, stream>>>(wq, wqkvt, 512, 512);
    wtrans<<<dim3(16, 16), blk, 0, stream>>>(wk, wqkvt + 512 * 512, 512, 512);
    wtrans<<<dim3(16, 16), blk, 0, stream>>>(wv, wqkvt + 1024 * 512, 512, 512);
    wtrans<<<dim3(16, 16), blk, 0, stream>>>(wo, wot, 512, 512);
    wtrans<<<dim3(64, 16), blk, 0, stream>>>(w1, w1t, 512, 2048);
    wtrans<<<dim3(16, 64), blk, 0, stream>>>(w2, w2t, 2048, 512);
    hipMemcpyAsync(bqkv,        bq, 512 * 4, hipMemcpyDeviceToDevice, stream);
    hipMemcpyAsync(bqkv + 512,  bk, 512 * 4, hipMemcpyDeviceToDevice, stream);
    hipMemcpyAsync(bqkv + 1024, bv, 512 * 4, hipMemcpyDeviceToDevice, stream);

    // --- qkv = xb @ [wq|wk|wv] + b -> bf16 [M][1536]   (128x128 tiles)
    gemm_bf16<2,2,4,4,1,0><<<dim3(12, 64), blk, 0, stream>>>(xb, wqkvt, bqkv, qkv, 512, 1536);

    // --- v transpose -> vt
    vtrans<<<dim3(32, 32), blk, 0, stream>>>(qkv, vt);

    // --- causal flash attention (MFMA, KB=128, LPT 1D grid) -> ctx bf16
    attn_mfma<<<dim3(1024), blk, 0, stream>>>(qkv, vt, ctx);

    // --- attnout = ctx @ wo + bo (fp32)   (64x128 tiles -> 512 blocks)
    gemm_bf16<1,4,4,2,0,0><<<dim3(4, 128), blk, 0, stream>>>(ctx, wot, bo, attnout, 512, 512);

    // --- h = LN(x + attnout) (fp32 + bf16 copy)
    addln_kernel<1><<<dim3(M_ / 4), blk, 0, stream>>>(x, attnout, g1, be1, h, hb);

    // --- ffn1 = relu(hb @ w1 + b1) -> bf16 [M][2048]   (128x128 tiles)
    gemm_bf16<2,2,4,4,1,1><<<dim3(16, 64), blk, 0, stream>>>(hb, w1t, b1, ffn1b, 512, 2048);

    // --- ffn2 = ffn1 @ w2 + b2 (fp32)   (64x128 tiles)
    gemm_bf16<1,4,4,2,0,0><<<dim3(4, 128), blk, 0, stream>>>(ffn1b, w2t, b2, ffn2, 2048, 512);

    // --- out = LN(h + ffn2)
    addln_kernel<0><<<dim3(M_ / 4), blk, 0, stream>>>(h, ffn2, g2, be2, out, nullptr);
}

// Round 5
// 317.053 us; speedup vs baseline: 4.9350x; 1.0243x over previous
//
#include <hip/hip_runtime.h>
#include <math.h>

#define D_   512
#define H_   8
#define DK_  64
#define FF_  2048
#define S_   2048
#define B_   4
#define M_   (B_*S_)     // 8192
#define EPS_ 1e-5f

typedef __attribute__((ext_vector_type(8))) short bf16x8;
typedef __attribute__((ext_vector_type(4))) float f32x4;

__device__ inline unsigned short f2b(float f) {
    unsigned u = __builtin_bit_cast(unsigned, f);
    unsigned r = (u + 0x7FFFu + ((u >> 16) & 1u)) >> 16;
    return (unsigned short)r;
}
// truncation (1 VALU op) — used only for P in [0,1]
__device__ inline unsigned short f2b_trunc(float f) {
    return (unsigned short)(__builtin_bit_cast(unsigned, f) >> 16);
}

// async 16B global->LDS (m97). LDS dest must be wave-uniform base + lane*16.
__device__ __forceinline__ void async_cp16(const void* g, void* l) {
    __builtin_amdgcn_global_load_lds(
        (const __attribute__((address_space(1))) unsigned int*)g,
        (__attribute__((address_space(3))) unsigned int*)l, 16, 0, 0);
}

// ---------------------------------------------------------------------------
__global__ __launch_bounds__(256)
void convert_bf16(const float* __restrict__ src, unsigned short* __restrict__ dst)
{
    const int i = (blockIdx.x * 256 + threadIdx.x) * 8;
    const float4 a = *(const float4*)(src + i);
    const float4 b = *(const float4*)(src + i + 4);
    bf16x8 v;
    v[0] = (short)f2b(a.x); v[1] = (short)f2b(a.y);
    v[2] = (short)f2b(a.z); v[3] = (short)f2b(a.w);
    v[4] = (short)f2b(b.x); v[5] = (short)f2b(b.y);
    v[6] = (short)f2b(b.z); v[7] = (short)f2b(b.w);
    *(bf16x8*)(dst + i) = v;
}

// ---------------------------------------------------------------------------
// Generic weight transpose+convert: w [K][N] f32 -> wt [N][K] bf16.
// ---------------------------------------------------------------------------
__global__ __launch_bounds__(256)
void wtrans(const float* __restrict__ w, unsigned short* __restrict__ wt, int K, int N)
{
    __shared__ float L[32][33];
    const int k0 = blockIdx.y * 32, n0 = blockIdx.x * 32;
    const int x = threadIdx.x & 31, y = threadIdx.x >> 5;
#pragma unroll
    for (int i = 0; i < 4; i++)
        L[y + i * 8][x] = w[(size_t)(k0 + y + i * 8) * N + n0 + x];
    __syncthreads();
#pragma unroll
    for (int i = 0; i < 4; i++)
        wt[(size_t)(n0 + y + i * 8) * K + k0 + x] = f2b(L[x][y + i * 8]);
}

// ---------------------------------------------------------------------------
// Fused transpose for the four 512x512 weights (wq,wk,wv -> wqkvt; wo -> wot)
// + packs bqkv while it's at it. Replaces 4 dispatches + 3 memcpys.
// ---------------------------------------------------------------------------
__global__ __launch_bounds__(256)
void wtrans4(const float* __restrict__ wq, const float* __restrict__ wk,
             const float* __restrict__ wv, const float* __restrict__ wo,
             const float* __restrict__ bq, const float* __restrict__ bk,
             const float* __restrict__ bv,
             unsigned short* __restrict__ wqkvt, unsigned short* __restrict__ wot,
             float* __restrict__ bqkv)
{
    __shared__ float L[32][33];
    const int z = blockIdx.z;
    const float* w = (z == 0) ? wq : (z == 1) ? wk : (z == 2) ? wv : wo;
    unsigned short* wt = (z < 3) ? (wqkvt + (size_t)z * 512 * 512) : wot;
    const int k0 = blockIdx.y * 32, n0 = blockIdx.x * 32;
    const int x = threadIdx.x & 31, y = threadIdx.x >> 5;
#pragma unroll
    for (int i = 0; i < 4; i++)
        L[y + i * 8][x] = w[(size_t)(k0 + y + i * 8) * 512 + n0 + x];
    __syncthreads();
#pragma unroll
    for (int i = 0; i < 4; i++)
        wt[(size_t)(n0 + y + i * 8) * 512 + k0 + x] = f2b(L[x][y + i * 8]);
    if (z < 3 && blockIdx.x == 0 && blockIdx.y == 0) {
        const float* bsrc = (z == 0) ? bq : (z == 1) ? bk : bv;
        const int t = threadIdx.x;
        bqkv[z * 512 + t]       = bsrc[t];
        bqkv[z * 512 + 256 + t] = bsrc[256 + t];
    }
}

// ---------------------------------------------------------------------------
// bf16 MFMA GEMM (m97 structure). Tile BM x BN, BK=32, 4 waves.
// A [M][K] bf16, Bt [N][K] bf16. Optional fp32 residual add (RES, C-layout).
// ---------------------------------------------------------------------------
template<int WR, int WC, int MT, int NT, int OUTB, int RELU, int RESADD>
__global__ __launch_bounds__(256)
void gemm_bf16(const unsigned short* __restrict__ A, const unsigned short* __restrict__ Bt,
               const float* __restrict__ bias, const float* __restrict__ RES,
               void* __restrict__ Cv, int K, int ldc)
{
    constexpr int BM = WR * MT * 16;
    constexpr int BN = WC * NT * 16;
    __shared__ unsigned short As[BM * 32];
    __shared__ unsigned short Bs[BN * 32];

    const int tid  = threadIdx.x;
    const int lane = tid & 63;
    const int w    = tid >> 6;
    const int wr   = w / WC, wc = w % WC;
    const int quad = lane >> 4;
    const int l15  = lane & 15;
    const int n0   = blockIdx.x * BN;
    const int m0   = blockIdx.y * BM;

    f32x4 acc[MT][NT];
#pragma unroll
    for (int i = 0; i < MT; i++)
#pragma unroll
        for (int j = 0; j < NT; j++) acc[i][j] = (f32x4){0.f, 0.f, 0.f, 0.f};

    constexpr int CA = BM / 64;
    constexpr int CB = BN / 64;

    for (int k0 = 0; k0 < K; k0 += 32) {
        __syncthreads();
#pragma unroll
        for (int i = 0; i < CA; i++) {
            const int c = tid + i * 256;
            async_cp16(&A[(size_t)(m0 + (c >> 2)) * K + k0 + (c & 3) * 8], &As[c * 8]);
        }
#pragma unroll
        for (int i = 0; i < CB; i++) {
            const int c = tid + i * 256;
            async_cp16(&Bt[(size_t)(n0 + (c >> 2)) * K + k0 + (c & 3) * 8], &Bs[c * 8]);
        }
        __builtin_amdgcn_s_waitcnt(0x0f70);       // vmcnt(0)
        __syncthreads();

        bf16x8 af[MT], bfr[NT];
#pragma unroll
        for (int t = 0; t < MT; t++)
            af[t]  = *(const bf16x8*)&As[(wr * MT * 16 + t * 16 + l15) * 32 + quad * 8];
#pragma unroll
        for (int t = 0; t < NT; t++)
            bfr[t] = *(const bf16x8*)&Bs[(wc * NT * 16 + t * 16 + l15) * 32 + quad * 8];
#pragma unroll
        for (int mt = 0; mt < MT; mt++)
#pragma unroll
            for (int nt = 0; nt < NT; nt++)
                acc[mt][nt] = __builtin_amdgcn_mfma_f32_16x16x32_bf16(
                    af[mt], bfr[nt], acc[mt][nt], 0, 0, 0);
    }

    // epilogue: C/D layout col=lane&15, row=quad*4+reg
#pragma unroll
    for (int mt = 0; mt < MT; mt++) {
        const int rowb = m0 + wr * MT * 16 + mt * 16 + quad * 4;
#pragma unroll
        for (int nt = 0; nt < NT; nt++) {
            const int col = n0 + wc * NT * 16 + nt * 16 + l15;
            const float bv = bias[col];
#pragma unroll
            for (int r = 0; r < 4; r++) {
                const size_t idx = (size_t)(rowb + r) * ldc + col;
                float v = acc[mt][nt][r] + bv;
                if (RESADD) v += RES[idx];
                if (RELU)   v = fmaxf(v, 0.f);
                if (OUTB) ((unsigned short*)Cv)[idx] = f2b(v);
                else      ((float*)Cv)[idx] = v;
            }
        }
    }
}

// ---------------------------------------------------------------------------
// V transpose: qkv v-part [s][dk] per (b,h) -> vt [(b*8+h)*64+dk][s] bf16.
// ---------------------------------------------------------------------------
__global__ __launch_bounds__(256)
void vtrans(const unsigned short* __restrict__ qkv, unsigned short* __restrict__ vt)
{
    __shared__ unsigned short L[64][72];
    const int s0 = blockIdx.x * 64;
    const int bh = blockIdx.y;
    const int b  = bh >> 3, hh = bh & 7;
    const int tid = threadIdx.x;
    const unsigned short* src = qkv + (size_t)(b * S_) * 1536 + 1024 + hh * 64;
#pragma unroll
    for (int i = 0; i < 2; i++) {
        const int c = tid + i * 256;
        const int r = c >> 3, sub = (c & 7) * 8;
        *(bf16x8*)&L[r][sub] = *(const bf16x8*)(src + (size_t)(s0 + r) * 1536 + sub);
    }
    __syncthreads();
    const int dk = tid >> 2;
    const int sc = (tid & 3) * 16;
    bf16x8 t0, t1;
#pragma unroll
    for (int j = 0; j < 8; j++) t0[j] = (short)L[sc + j][dk];
#pragma unroll
    for (int j = 0; j < 8; j++) t1[j] = (short)L[sc + 8 + j][dk];
    unsigned short* dst = vt + (size_t)(bh * 64 + dk) * S_ + s0 + sc;
    *(bf16x8*)(dst)     = t0;
    *(bf16x8*)(dst + 8) = t1;
}

// ---------------------------------------------------------------------------
// Causal flash attention, bf16 MFMA. BQ=128 (8 waves x 16 q-rows), KB=128.
// Raw-domain running max (1 fma + exp2 per element), truncated P convert,
// diag-masked PV chunk skip. 512-thread blocks, LPT 1D grid.
// ---------------------------------------------------------------------------
__global__ __launch_bounds__(512)
void attn_mfma(const unsigned short* __restrict__ qkv,
               const unsigned short* __restrict__ vt,
               unsigned short* __restrict__ ctx)
{
    constexpr int LDP = 136;
    __shared__ unsigned short Ks[128 * 64];   // [kr][d], chunk^=(kr&7)
    __shared__ unsigned short Vs[64 * 128];   // [dk][kr], chunk^=(dk&15)
    __shared__ unsigned short Ps[8][16 * LDP];

    const int tid  = threadIdx.x;
    const int lane = tid & 63;
    const int w    = tid >> 6;                // 0..7
    const int quad = lane >> 4;
    const int l15  = lane & 15;
    const int bid  = blockIdx.x;
    const int qb   = 15 - (bid >> 5);         // LPT: heaviest first
    const int bh   = bid & 31;
    const int b    = bh >> 3, hh = bh & 7;

    const unsigned short* qbase = qkv + (size_t)(b * S_) * 1536 + hh * 64;
    const unsigned short* kbase = qbase + 512;
    const unsigned short* vtb   = vt + (size_t)bh * 64 * S_;

    bf16x8 qf[2];
    {
        const unsigned short* qr = qbase + (size_t)(qb * 128 + w * 16 + l15) * 1536;
        qf[0] = *(const bf16x8*)(qr + quad * 8);
        qf[1] = *(const bf16x8*)(qr + 32 + quad * 8);
    }

    f32x4 Oacc[4];
#pragma unroll
    for (int i = 0; i < 4; i++) Oacc[i] = (f32x4){0.f, 0.f, 0.f, 0.f};
    float mrow[4], lrow[4];                    // mrow in RAW score domain
#pragma unroll
    for (int r = 0; r < 4; r++) { mrow[r] = -1.0e30f; lrow[r] = 0.f; }

    const float SCL = 0.125f * 1.44269504089f; // 1/sqrt(64) * log2(e)
    const int   qg0 = qb * 128 + w * 16 + quad * 4;
    const int   klim = qb * 128 + w * 16 + 15;
    const int   kcmax_diag = (w * 16 + 15) / 32 + 1;
    unsigned short* pw = &Ps[w][0];

    for (int kb = 0; kb <= qb; kb++) {
        __syncthreads();
#pragma unroll
        for (int i = 0; i < 2; i++) {          // K tile: 1024 chunks / 512 thr
            const int c = tid + i * 512;
            const int row = c >> 3;
            const int l = (c & 7) ^ (row & 7);
            async_cp16(kbase + (size_t)(kb * 128 + row) * 1536 + l * 8, &Ks[c * 8]);
        }
#pragma unroll
        for (int i = 0; i < 2; i++) {          // V^T tile
            const int c = tid + i * 512;
            const int row = c >> 4;
            const int l = (c & 15) ^ (row & 15);
            async_cp16(vtb + (size_t)row * S_ + kb * 128 + l * 8, &Vs[c * 8]);
        }
        __builtin_amdgcn_s_waitcnt(0x0f70);    // vmcnt(0)
        __syncthreads();

        const bool diag = (kb == qb);

        // ---- S = Q @ K^T over 8 key tiles (skip fully-masked tiles)
        f32x4 sacc[8];
#pragma unroll
        for (int nt = 0; nt < 8; nt++) sacc[nt] = (f32x4){0.f, 0.f, 0.f, 0.f};
#pragma unroll
        for (int nt = 0; nt < 8; nt++) {
            if (diag && (kb * 128 + nt * 16 > klim)) continue;
#pragma unroll
            for (int kc = 0; kc < 2; kc++) {
                const int phys = (kc * 4 + quad) ^ (l15 & 7);
                const bf16x8 kf = *(const bf16x8*)&Ks[(nt * 16 + l15) * 64 + phys * 8];
                sacc[nt] = __builtin_amdgcn_mfma_f32_16x16x32_bf16(qf[kc], kf, sacc[nt], 0, 0, 0);
            }
        }

        // ---- online softmax, raw-domain max
        float alpha[4];
#pragma unroll
        for (int r = 0; r < 4; r++) {
            float sv[8];
#pragma unroll
            for (int nt = 0; nt < 8; nt++) {
                float s = sacc[nt][r];
                if (diag) {
                    const int kg = kb * 128 + nt * 16 + l15;
                    if (kg > qg0 + r) s = -1.0e9f;
                }
                sv[nt] = s;
            }
            float m0 = fmaxf(fmaxf(sv[0], sv[1]), fmaxf(sv[2], sv[3]));
            float m1 = fmaxf(fmaxf(sv[4], sv[5]), fmaxf(sv[6], sv[7]));
            float rmax = fmaxf(m0, m1);
#pragma unroll
            for (int m = 1; m < 16; m <<= 1) rmax = fmaxf(rmax, __shfl_xor(rmax, m));
            const float mnew = fmaxf(mrow[r], rmax);
            alpha[r] = exp2f((mrow[r] - mnew) * SCL);
            const float negms = -mnew * SCL;
            float rsum = 0.f;
#pragma unroll
            for (int nt = 0; nt < 8; nt++) {
                sv[nt] = exp2f(fmaf(sv[nt], SCL, negms));  // fma + exp2 only
                rsum += sv[nt];
            }
#pragma unroll
            for (int m = 1; m < 16; m <<= 1) rsum += __shfl_xor(rsum, m);
            lrow[r] = lrow[r] * alpha[r] + rsum;
            mrow[r] = mnew;
#pragma unroll
            for (int nt = 0; nt < 8; nt++)
                pw[(quad * 4 + r) * LDP + nt * 16 + l15] = f2b_trunc(sv[nt]);
        }
#pragma unroll
        for (int nt = 0; nt < 4; nt++)
#pragma unroll
            for (int r = 0; r < 4; r++) Oacc[nt][r] *= alpha[r];

        // ---- O += P @ V (skip fully-zero P chunks on diag iters)
        const int kcmax = diag ? kcmax_diag : 4;
#pragma unroll
        for (int kc = 0; kc < 4; kc++) {
            if (kc < kcmax) {
                const bf16x8 af = *(const bf16x8*)&pw[l15 * LDP + kc * 32 + quad * 8];
#pragma unroll
                for (int nt = 0; nt < 4; nt++) {
                    const int phys = (kc * 4 + quad) ^ l15;
                    const bf16x8 vf = *(const bf16x8*)&Vs[(nt * 16 + l15) * 128 + phys * 8];
                    Oacc[nt] = __builtin_amdgcn_mfma_f32_16x16x32_bf16(af, vf, Oacc[nt], 0, 0, 0);
                }
            }
        }
    }

    const int orow = qb * 128 + w * 16 + quad * 4;
    unsigned short* cb = ctx + (size_t)(b * S_) * 512 + hh * 64;
#pragma unroll
    for (int r = 0; r < 4; r++) {
        const float inv = 1.f / lrow[r];
#pragma unroll
        for (int nt = 0; nt < 4; nt++)
            cb[(size_t)(orow + r) * 512 + nt * 16 + l15] = f2b(Oacc[nt][r] * inv);
    }
}

// ---------------------------------------------------------------------------
// out = LayerNorm(s) * g + be (s already holds residual+gemm).  1 wave/row.
// ---------------------------------------------------------------------------
template<int WB>
__global__ __launch_bounds__(256)
void ln_kernel(const float* __restrict__ s, const float* __restrict__ g,
               const float* __restrict__ be, float* __restrict__ out,
               unsigned short* __restrict__ outb)
{
    const int wave = threadIdx.x >> 6;
    const int lane = threadIdx.x & 63;
    const int row  = blockIdx.x * 4 + wave;
    const float* ps = s + (size_t)row * D_;
    const int c0 = lane * 4;

    float v[8];
    {
        const float4 a0 = *(const float4*)(ps + c0);
        const float4 a1 = *(const float4*)(ps + c0 + 256);
        v[0] = a0.x; v[1] = a0.y; v[2] = a0.z; v[3] = a0.w;
        v[4] = a1.x; v[5] = a1.y; v[6] = a1.z; v[7] = a1.w;
    }

    float sum = 0.f;
#pragma unroll
    for (int i = 0; i < 8; i++) sum += v[i];
#pragma unroll
    for (int m = 1; m < 64; m <<= 1) sum += __shfl_xor(sum, m);
    const float mu = sum * (1.f / D_);

    float sq = 0.f;
#pragma unroll
    for (int i = 0; i < 8; i++) { const float d = v[i] - mu; sq += d * d; }
#pragma unroll
    for (int m = 1; m < 64; m <<= 1) sq += __shfl_xor(sq, m);
    const float rstd = rsqrtf(sq * (1.f / D_) + EPS_);

    const float4 g0 = *(const float4*)(g + c0);
    const float4 b0 = *(const float4*)(be + c0);
    const float4 g1 = *(const float4*)(g + c0 + 256);
    const float4 b1 = *(const float4*)(be + c0 + 256);

    float o[8];
    o[0] = (v[0] - mu) * rstd * g0.x + b0.x;
    o[1] = (v[1] - mu) * rstd * g0.y + b0.y;
    o[2] = (v[2] - mu) * rstd * g0.z + b0.z;
    o[3] = (v[3] - mu) * rstd * g0.w + b0.w;
    o[4] = (v[4] - mu) * rstd * g1.x + b1.x;
    o[5] = (v[5] - mu) * rstd * g1.y + b1.y;
    o[6] = (v[6] - mu) * rstd * g1.z + b1.z;
    o[7] = (v[7] - mu) * rstd * g1.w + b1.w;

    *(float4*)(out + (size_t)row * D_ + c0)       = *(float4*)&o[0];
    *(float4*)(out + (size_t)row * D_ + c0 + 256) = *(float4*)&o[4];
    if (WB) {
        short4 vb0 = (short4){(short)f2b(o[0]), (short)f2b(o[1]), (short)f2b(o[2]), (short)f2b(o[3])};
        short4 vb1 = (short4){(short)f2b(o[4]), (short)f2b(o[5]), (short)f2b(o[6]), (short)f2b(o[7])};
        *(short4*)(outb + (size_t)row * D_ + c0)       = vb0;
        *(short4*)(outb + (size_t)row * D_ + c0 + 256) = vb1;
    }
}

// ---------------------------------------------------------------------------
extern "C" void kernel_launch(void* const* d_in, const int* in_sizes, int n_in,
                              void* d_out, int out_size, void* d_ws, size_t ws_size,
                              hipStream_t stream)
{
    const float* x  = (const float*)d_in[0];
    const float* wq = (const float*)d_in[2];
    const float* bq = (const float*)d_in[3];
    const float* wk = (const float*)d_in[4];
    const float* bk = (const float*)d_in[5];
    const float* wv = (const float*)d_in[6];
    const float* bv = (const float*)d_in[7];
    const float* wo = (const float*)d_in[8];
    const float* bo = (const float*)d_in[9];
    const float* w1 = (const float*)d_in[10];
    const float* b1 = (const float*)d_in[11];
    const float* w2 = (const float*)d_in[12];
    const float* b2 = (const float*)d_in[13];
    const float* g1 = (const float*)d_in[14];
    const float* be1= (const float*)d_in[15];
    const float* g2 = (const float*)d_in[16];
    const float* be2= (const float*)d_in[17];
    float* out = (float*)d_out;

    const size_t MB = 1048576;
    char* w8 = (char*)d_ws;
    unsigned short* wqkvt = (unsigned short*)(w8 + 0);            // 1536x512 bf16
    unsigned short* wot   = (unsigned short*)(w8 + 1572864);      // 512x512
    unsigned short* w1t   = (unsigned short*)(w8 + 2097152);      // 2048x512
    unsigned short* w2t   = (unsigned short*)(w8 + 4194304);      // 512x2048
    float*          bqkv  = (float*)(w8 + 6291456);               // 1536 f32
    unsigned short* qkv   = (unsigned short*)(w8 + 8 * MB);       // 24 MB (later ffn1b)
    unsigned short* ffn1b = qkv;
    unsigned short* xb    = (unsigned short*)(w8 + 40 * MB);      // 8 MB (later ctx)
    unsigned short* ctx   = xb;
    unsigned short* vt    = (unsigned short*)(w8 + 48 * MB);      // 8 MB (later hb)
    unsigned short* hb    = vt;
    float*          pre   = (float*)(w8 + 56 * MB);               // 16 MB (x+attn, then h+ffn2)
    float*          h     = (float*)(w8 + 72 * MB);               // 16 MB

    const dim3 blk(256);

    convert_bf16<<<dim3(M_ * D_ / 8 / 256), blk, 0, stream>>>(x, xb);
    wtrans4<<<dim3(16, 16, 4), blk, 0, stream>>>(wq, wk, wv, wo, bq, bk, bv, wqkvt, wot, bqkv);
    wtrans<<<dim3(64, 16), blk, 0, stream>>>(w1, w1t, 512, 2048);
    wtrans<<<dim3(16, 64), blk, 0, stream>>>(w2, w2t, 2048, 512);

    // qkv = xb @ [wq|wk|wv] + b -> bf16 [M][1536]
    gemm_bf16<2,2,4,4,1,0,0><<<dim3(12, 64), blk, 0, stream>>>(xb, wqkvt, bqkv, nullptr, qkv, 512, 1536);

    vtrans<<<dim3(32, 32), blk, 0, stream>>>(qkv, vt);

    // causal flash attention (BQ=128, 512 threads) -> ctx bf16
    attn_mfma<<<dim3(512), dim3(512), 0, stream>>>(qkv, vt, ctx);

    // pre = x + ctx @ wo + bo (fp32, residual fused)
    gemm_bf16<2,2,4,4,0,0,1><<<dim3(4, 64), blk, 0, stream>>>(ctx, wot, bo, x, pre, 512, 512);

    // h = LN(pre), also bf16 copy hb
    ln_kernel<1><<<dim3(M_ / 4), blk, 0, stream>>>(pre, g1, be1, h, hb);

    // ffn1 = relu(hb @ w1 + b1) -> bf16 [M][2048]
    gemm_bf16<2,2,4,4,1,1,0><<<dim3(16, 64), blk, 0, stream>>>(hb, w1t, b1, nullptr, ffn1b, 512, 2048);

    // pre = h + ffn1 @ w2 + b2 (fp32, residual fused)
    gemm_bf16<2,2,4,4,0,0,1><<<dim3(4, 64), blk, 0, stream>>>(ffn1b, w2t, b2, h, pre, 2048, 512);

    // out = LN(pre)
    ln_kernel<0><<<dim3(M_ / 4), blk, 0, stream>>>(pre, g2, be2, out, nullptr);
}